// Round 23
// baseline (183.819 us; speedup 1.0000x reference)
//
#include <hip/hip_runtime.h>
#include <hip/hip_bf16.h>
#include <math.h>

// ---- constants for this problem ----
#define BATCH 4
#define SEQ   2048
#define DM    1024
#define NHEAD 16
#define HDIM  64
#define MROWS (BATCH*SEQ)   // 8192

typedef float f32x4 __attribute__((ext_vector_type(4)));
typedef float f32x16 __attribute__((ext_vector_type(16)));
typedef short bf16x8 __attribute__((ext_vector_type(8)));  // 8 bf16 in 4 VGPRs
typedef unsigned int u32x4 __attribute__((ext_vector_type(4)));

typedef __attribute__((address_space(1))) unsigned int as1_u32;
typedef __attribute__((address_space(3))) unsigned int as3_u32;

__device__ __forceinline__ void gld16(const void* g, void* l) {
    // async global->LDS, 16B per lane; LDS dest = wave-uniform base + lane*16
    __builtin_amdgcn_global_load_lds((const as1_u32*)g, (as3_u32*)l, 16, 0, 0);
}

__device__ __forceinline__ unsigned short f2bf(float f) {
    unsigned int u = __float_as_uint(f);
    u += 0x7FFFu + ((u >> 16) & 1u);   // RNE
    return (unsigned short)(u >> 16);
}

__device__ __forceinline__ unsigned int pack2bf(float a, float b) {
    return (unsigned int)f2bf(a) | ((unsigned int)f2bf(b) << 16);
}

__device__ __forceinline__ float fexp2(float x) {
    float r;
    asm("v_exp_f32 %0, %1" : "=v"(r) : "v"(x));
    return r;
}

__device__ __forceinline__ unsigned int cvtpk2(float lo, float hi) {
    unsigned int r;
    asm("v_cvt_pk_bf16_f32 %0, %1, %2" : "=v"(r) : "v"(lo), "v"(hi));
    return r;
}

// lmode: 0 = Q rows (live iff s < ceil32(ql));
//        1 = K rows (skip ALL if vl<=0, else s < ceil64(vl));
//        2 = V rows (ALL if vl<=0, else s < ceil64(vl))
__device__ __forceinline__ int row_limit(int len, int lmode) {
    if (lmode == 0) return (len + 31) & ~31;
    if (lmode == 1) return (len <= 0) ? 0 : ((len + 63) & ~63);
    return (len <= 0) ? SEQ : ((len + 63) & ~63);
}

// ---------------- convert X (fp32 -> bf16), fused Q/K/V, length-skipped ----------------
__global__ __launch_bounds__(256) void convx3_kernel(const float* __restrict__ Q,
                                                     const float* __restrict__ K,
                                                     const float* __restrict__ V,
                                                     unsigned short* __restrict__ Xq,
                                                     unsigned short* __restrict__ Xk,
                                                     unsigned short* __restrict__ Xv,
                                                     const int* __restrict__ Qlen,
                                                     const int* __restrict__ Vlen,
                                                     int zoff) {
    const int z = blockIdx.y + zoff;
    const float* in = (z == 0) ? Q : (z == 1) ? K : V;
    unsigned short* out = (z == 0) ? Xq : (z == 1) ? Xk : Xv;
    int i = blockIdx.x * 256 + threadIdx.x;   // 8-float units; 128 per row
    int row = i >> 7;
    int b = row >> 11, s = row & 2047;
    int lim = (z == 0) ? row_limit(Qlen[b], 0) : row_limit(Vlen[b], z);
    if (s >= lim) return;   // skipped rows never read unmasked
    const float4* p = reinterpret_cast<const float4*>(in) + (size_t)i * 2;
    float4 a = p[0], v = p[1];
    uint4 r;
    r.x = pack2bf(a.x, a.y);
    r.y = pack2bf(a.z, a.w);
    r.z = pack2bf(v.x, v.y);
    r.w = pack2bf(v.z, v.w);
    reinterpret_cast<uint4*>(out)[i] = r;
}

// ---------------- convert + transpose W: [K][N] f32 -> [N][K] bf16, *scale, fused ----------------
__global__ __launch_bounds__(256) void convw3_kernel(const float* __restrict__ WQ,
                                                     const float* __restrict__ WK,
                                                     const float* __restrict__ WV,
                                                     unsigned short* __restrict__ Oq,
                                                     unsigned short* __restrict__ Ok,
                                                     unsigned short* __restrict__ Ov,
                                                     int zoff) {
    const int z = blockIdx.z + zoff;
    const float* in = (z == 0) ? WQ : (z == 1) ? WK : WV;
    unsigned short* out = (z == 0) ? Oq : (z == 1) ? Ok : Ov;
    const float scale = (z == 0) ? 0.125f * 1.44269504088896340736f : 1.0f;
    __shared__ float tile[64][65];
    int n0 = blockIdx.x * 64, k0 = blockIdx.y * 64;
    int tx = threadIdx.x, ty = threadIdx.y;  // (64,4)
#pragma unroll
    for (int i = 0; i < 64; i += 4)
        tile[ty + i][tx] = in[(size_t)(k0 + ty + i) * DM + n0 + tx];
    __syncthreads();
#pragma unroll
    for (int i = 0; i < 64; i += 4)
        out[(size_t)(n0 + ty + i) * DM + k0 + tx] = f2bf(tile[tx][ty + i] * scale);
}

// ---------------- fused GEMM: z selects (A,W,out,mode) ----------------
// z=0: q = Xq@WQt -> [B,H,S,D]; z=1: k = Xk@WKt -> [B,H,S,D]; z=2: v -> [B,H,D,S]
// R19-proven form (empirical floor ~62us): BK=32 counted-vmcnt + T2 swizzle + XCD remap.
__global__ __launch_bounds__(256) void gemm3_kernel(const unsigned short* __restrict__ Xq,
                                                    const unsigned short* __restrict__ Xk,
                                                    const unsigned short* __restrict__ Xv,
                                                    const unsigned short* __restrict__ Wq,
                                                    const unsigned short* __restrict__ Wk,
                                                    const unsigned short* __restrict__ Wv,
                                                    unsigned short* __restrict__ qo,
                                                    unsigned short* __restrict__ ko,
                                                    unsigned short* __restrict__ vo,
                                                    const int* __restrict__ Qlen,
                                                    const int* __restrict__ Vlen,
                                                    int zoff) {
    const int z = blockIdx.z + zoff;
    const unsigned short* A = (z == 0) ? Xq : (z == 1) ? Xk : Xv;
    const unsigned short* Bt = (z == 0) ? Wq : (z == 1) ? Wk : Wv;
    unsigned short* out = (z == 0) ? qo : (z == 1) ? ko : vo;
    const int vmode = (z == 2);
    // bijective tile remap: mt = (by>>3)*8 + bx, nt = by&7  (XCD = bx)
    const int mt_ = (blockIdx.y >> 3) * 8 + blockIdx.x;
    const int nt_ = blockIdx.y & 7;
    const int m0 = mt_ << 7, n0 = nt_ << 7;
    {   // block-uniform length skip: 128-row tile lies within one batch
        int b = m0 >> 11, s0 = m0 & 2047;
        int len = (z == 0) ? Qlen[b] : Vlen[b];
        if (s0 >= row_limit(len, z)) return;
    }
    __shared__ unsigned short lA[2][128 * 32];
    __shared__ unsigned short lB[2][128 * 32];
    const int tid = threadIdx.x, lane = tid & 63, wave = tid >> 6;
    const int wr = wave >> 1, wc = wave & 1;
    const int col = lane & 15, grp = lane >> 4;

    f32x4 acc[4][4] = {};

    const int srow = tid >> 2;
    const int sx = (tid & 3) ^ (srow & 3);   // pre-swizzled source segment (rule #21)
    const unsigned short* srcA0 = A + (size_t)(m0 + srow) * DM + sx * 8;
    const unsigned short* srcA1 = srcA0 + (size_t)64 * DM;   // (row+64)&3 == row&3
    const unsigned short* srcB0 = Bt + (size_t)(n0 + srow) * DM + sx * 8;
    const unsigned short* srcB1 = srcB0 + (size_t)64 * DM;

#define STAGEG(BF, K0) do {                                   \
        gld16(srcA0 + (K0), &lA[BF][wave * 512]);             \
        gld16(srcA1 + (K0), &lA[BF][2048 + wave * 512]);      \
        gld16(srcB0 + (K0), &lB[BF][wave * 512]);             \
        gld16(srcB1 + (K0), &lB[BF][2048 + wave * 512]);      \
    } while (0)

    STAGEG(0, 0);                          // prologue prefetch (stays in flight)

    const int xs = (grp ^ (col & 3)) * 8;  // swizzled read segment (row&3 == col&3)
    int bf = 0;
    for (int k0 = 0; k0 < DM; k0 += 32) {
        if (k0 + 32 < DM) {
            STAGEG(bf ^ 1, k0 + 32);       // issue next tile (8 outstanding now)
            asm volatile("s_waitcnt vmcnt(4)" ::: "memory");   // cur tile's 4 landed
        } else {
            asm volatile("s_waitcnt vmcnt(0)" ::: "memory");
        }
        __builtin_amdgcn_sched_barrier(0);
        __builtin_amdgcn_s_barrier();      // every wave confirmed its cur-tile quarter
        __builtin_amdgcn_sched_barrier(0);

        bf16x8 af[4], bfr[4];
#pragma unroll
        for (int mt = 0; mt < 4; mt++)
            af[mt] = *reinterpret_cast<const bf16x8*>(&lA[bf][(wr * 64 + mt * 16 + col) * 32 + xs]);
#pragma unroll
        for (int nt = 0; nt < 4; nt++)
            bfr[nt] = *reinterpret_cast<const bf16x8*>(&lB[bf][(wc * 64 + nt * 16 + col) * 32 + xs]);
#pragma unroll
        for (int mt = 0; mt < 4; mt++)
#pragma unroll
            for (int nt = 0; nt < 4; nt++)
                acc[mt][nt] = __builtin_amdgcn_mfma_f32_16x16x32_bf16(af[mt], bfr[nt], acc[mt][nt], 0, 0, 0);

        __builtin_amdgcn_sched_barrier(0);
        __builtin_amdgcn_s_barrier();      // all reads of bf done (MFMA forced lgkm drain)
        __builtin_amdgcn_sched_barrier(0);
        bf ^= 1;
    }
#undef STAGEG

#pragma unroll
    for (int mt = 0; mt < 4; mt++) {
        int rowb = m0 + wr * 64 + mt * 16 + grp * 4;
#pragma unroll
        for (int nt = 0; nt < 4; nt++) {
            int c = n0 + wc * 64 + nt * 16 + col;
            int h = c >> 6, d = c & 63;
            if (vmode == 0) {
#pragma unroll
                for (int r = 0; r < 4; r++) {
                    int rr = rowb + r;
                    int b = rr >> 11, s = rr & 2047;
                    out[((((size_t)(b * NHEAD + h)) << 11) + s) * HDIM + d] = f2bf(acc[mt][nt][r]);
                }
            } else {
                // transposed: 4 consecutive s -> one 8B store at [(b,h,d)][s]
                int b = rowb >> 11, s = rowb & 2047;
                uint2 pk;
                pk.x = pack2bf(acc[mt][nt][0], acc[mt][nt][1]);
                pk.y = pack2bf(acc[mt][nt][2], acc[mt][nt][3]);
                *reinterpret_cast<uint2*>(
                    &out[(((size_t)(b * NHEAD + h)) * HDIM + d) * SEQ + s]) = pk;
            }
        }
    }
}

// ---------------- flash attention: 128 q-rows/block, 16 waves = 4 q-subtiles x 4 KV-streams ----------------
// grid 1024; block 1024. Wave (qw,kw): qw owns q-rows [q0+32qw,+32); kw walks KV
// tiles kw, kw+4, ... (private dbuf LDS per stream, 128KB). Counted-vmcnt + raw
// barriers per round (proven). Heavy-batch tail: 4 waves/SIMD, 8-round chain.
// End: 2-stage hypercube combine (kw^1 on dt-halves, kw^2 on 16-col quarters).
__global__ __launch_bounds__(1024) void flash_kernel(const unsigned short* __restrict__ qm,
                                                     const unsigned short* __restrict__ km,
                                                     const unsigned short* __restrict__ vtm,
                                                     const int* __restrict__ Qlen,
                                                     const int* __restrict__ Vlen,
                                                     float* __restrict__ out) {
    // XCD swizzle: XCD = raw%8 = h%8 -> each XCD streams only 2 heads' K/V
    const int raw = blockIdx.x;
    const int x = raw & 7, y = raw >> 3;
    const int qt = y & 15, z = y >> 4;
    const int h = x + ((z & 1) << 3);
    const int b = z >> 1;
    const int q0 = qt << 7;                  // 128 q-rows per block
    const int tid = threadIdx.x;
    const int lane = tid & 63, wv = tid >> 6;   // 16 waves
    const int qw = wv & 3, kw = wv >> 2;        // kw in 0..3
    const int qI = lane & 31, hi = lane >> 5;
    const int ql = Qlen[b], vl = Vlen[b];
    const int qrow = q0 + qw * 32 + qI;      // this wave's q-row for this lane

    if (q0 >= ql) {  // block-uniform: whole 128-row tile query-masked -> zeros
        int r = tid >> 3;                    // 0..127
        int c0 = (tid & 7) * 8;              // 0..56
        float* p = out + (size_t)(b * SEQ + q0 + r) * DM + h * HDIM + c0;
        float4 z4 = {0.f, 0.f, 0.f, 0.f};
        reinterpret_cast<float4*>(p)[0] = z4;
        reinterpret_cast<float4*>(p)[1] = z4;
        return;
    }

    const bool uniform = (vl <= 0);      // fp32 ref collapse: uniform weights over ALL keys
    const int eff = uniform ? SEQ : vl;
    const int nkv = (eff + 63) >> 6;

    const size_t hb = ((size_t)(b * NHEAD + h)) << 11;  // *SEQ
    const unsigned short* qbase = qm + hb * HDIM;
    const unsigned short* kbase = km + hb * HDIM;
    const unsigned short* vbase = vtm + hb * HDIM;      // [64][SEQ] per (b,h)

    // per-stream double-buffered K tile [64 keys][64 d] and V^T tile [64 d][64 keys];
    // LDS[row][slot] holds global[row][slot ^ (row&7)]. 128 KB total.
    __shared__ __align__(16) unsigned short lsK[4][2][64 * 64];
    __shared__ __align__(16) unsigned short lsV[4][2][64 * 64];

    const int r8 = lane >> 3, cs = lane & 7;
    const int sxs = cs ^ r8;                              // (slot ^ (row&7))
    const size_t offK0 = (size_t)(qw * 16 + r8) * HDIM + sxs * 8;
    const size_t offK1 = offK0 + (size_t)8 * HDIM;
    const size_t offV0 = (size_t)(qw * 16 + r8) * SEQ + sxs * 8;
    const size_t offV1 = offV0 + (size_t)8 * SEQ;

#define STAGE(BF, T) do {                                                \
        const int kv0_ = (T) << 6;                                       \
        const unsigned short* gk_ = kbase + (size_t)kv0_ * HDIM;         \
        const unsigned short* gv_ = vbase + kv0_;                        \
        gld16(gk_ + offK0, &lsK[kw][BF][(qw * 16) * 64]);                \
        gld16(gk_ + offK1, &lsK[kw][BF][(qw * 16 + 8) * 64]);            \
        gld16(gv_ + offV0, &lsV[kw][BF][(qw * 16) * 64]);                \
        gld16(gv_ + offV1, &lsV[kw][BF][(qw * 16 + 8) * 64]);            \
    } while (0)

    // Q B-fragment (held all tiles): col j = q = qI, k-chunk = sp*16 + hi*8
    bf16x8 qB[4];
#pragma unroll
    for (int sp = 0; sp < 4; sp++)
        qB[sp] = *reinterpret_cast<const bf16x8*>(&qbase[(size_t)qrow * HDIM + sp * 16 + hi * 8]);

    f32x16 o_acc2[2] = {};
    float m = -3.0e38f, l = 0.f;
    const int q7 = qI & 7;                   // row&7 for all K/V rows this lane reads

    const int rounds = (nkv + 3) >> 2;
    if (kw < nkv) STAGE(0, kw);              // round-0 tile for own stream (in flight)

    int bf = 0;
    for (int r = 0; r < rounds; r++) {
        const int tcur = 4 * r + kw;
        const int tnext = tcur + 4;
        if (tnext < nkv) {
            STAGE(bf ^ 1, tnext);            // issue next tile (8 outstanding)
            asm volatile("s_waitcnt vmcnt(4)" ::: "memory");   // cur tile's 4 landed
        } else {
            asm volatile("s_waitcnt vmcnt(0)" ::: "memory");
        }
        __builtin_amdgcn_sched_barrier(0);
        __builtin_amdgcn_s_barrier();        // all waves' parts of cur tiles visible
        __builtin_amdgcn_sched_barrier(0);

        if (tcur < nkv) {
            const int kv0 = tcur << 6;

            // ---- S^T = K Q^T from LDS: two 32-key tiles ----
            f32x16 st2[2] = {};
            const unsigned short* Kb = &lsK[kw][bf][0];
#pragma unroll
            for (int kt = 0; kt < 2; kt++)
#pragma unroll
                for (int sp = 0; sp < 4; sp++) {
                    int xsk = (sp * 2 + hi) ^ q7;
                    bf16x8 ka = *reinterpret_cast<const bf16x8*>(&Kb[(kt * 32 + qI) * 64 + xsk * 8]);
                    st2[kt] = __builtin_amdgcn_mfma_f32_32x32x16_bf16(ka, qB[sp], st2[kt], 0, 0, 0);
                }

            // ---- mask: key(t,r) = kv0 + t*32 + (r&3) + 8*(r>>2) + 4*hi ----
            if (uniform) {
#pragma unroll
                for (int t = 0; t < 2; t++)
#pragma unroll
                    for (int rr = 0; rr < 16; rr++) st2[t][rr] = 0.f;
            } else if (kv0 + 64 > eff) {
#pragma unroll
                for (int t = 0; t < 2; t++)
#pragma unroll
                    for (int rr = 0; rr < 16; rr++)
                        if (kv0 + t * 32 + (rr & 3) + 8 * (rr >> 2) + 4 * hi >= eff)
                            st2[t][rr] = -1e30f;
            }

            // ---- online softmax: tree-max + T13 defer-rescale (THR=8, log2 domain) ----
            float tm8[8];
#pragma unroll
            for (int rr = 0; rr < 8; rr++)
                tm8[rr] = fmaxf(fmaxf(st2[0][rr], st2[0][rr + 8]), fmaxf(st2[1][rr], st2[1][rr + 8]));
            float tm4[4];
#pragma unroll
            for (int rr = 0; rr < 4; rr++) tm4[rr] = fmaxf(tm8[rr], tm8[rr + 4]);
            float mx = fmaxf(fmaxf(tm4[0], tm4[1]), fmaxf(tm4[2], tm4[3]));
            mx = fmaxf(mx, __shfl_xor(mx, 32));
            if (!__all(mx - m <= 8.0f)) {    // rescale only when max moved (wave-uniform)
                float mnew = fmaxf(m, mx);
                float sc = fexp2(m - mnew);
                l *= sc;
                o_acc2[0] *= sc;
                o_acc2[1] *= sc;
                m = mnew;
            }
#pragma unroll
            for (int t = 0; t < 2; t++)
#pragma unroll
                for (int rr = 0; rr < 16; rr++) st2[t][rr] = fexp2(st2[t][rr] - m);
            float ts8[8];
#pragma unroll
            for (int rr = 0; rr < 8; rr++)
                ts8[rr] = (st2[0][rr] + st2[0][rr + 8]) + (st2[1][rr] + st2[1][rr + 8]);
            float ts4[4];
#pragma unroll
            for (int rr = 0; rr < 4; rr++) ts4[rr] = ts8[rr] + ts8[rr + 4];
            float rs = (ts4[0] + ts4[1]) + (ts4[2] + ts4[3]);
            rs += __shfl_xor(rs, 32);
            l += rs;

            // ---- pack P pairs ----
            unsigned int pk[2][8];
#pragma unroll
            for (int t = 0; t < 2; t++)
#pragma unroll
                for (int p = 0; p < 8; p++)
                    pk[t][p] = cvtpk2(st2[t][2 * p], st2[t][2 * p + 1]);

            // ---- redistribute to PV B-frag (shfl_xor, proven) + PV MFMA ----
            const unsigned short* Vb = &lsV[kw][bf][0];
#pragma unroll
            for (int ks = 0; ks < 4; ks++) {
                const int t = ks >> 1, c = (ks & 1) * 4;
                unsigned int sel0 = pk[t][c], sel1 = pk[t][c + 1];
                unsigned int sel2 = pk[t][c + 2], sel3 = pk[t][c + 3];
                unsigned int sendA = hi ? sel0 : sel2;
                unsigned int sendB = hi ? sel1 : sel3;
                unsigned int gotA = __shfl_xor(sendA, 32);
                unsigned int gotB = __shfl_xor(sendB, 32);
                u32x4 u;
                u[0] = hi ? gotA : sel0;
                u[1] = hi ? gotB : sel1;
                u[2] = hi ? sel2 : gotA;
                u[3] = hi ? sel3 : gotB;
                bf16x8 pB = __builtin_bit_cast(bf16x8, u);
                int xsv = (ks * 2 + hi) ^ q7;
#pragma unroll
                for (int dt = 0; dt < 2; dt++) {
                    bf16x8 va = *reinterpret_cast<const bf16x8*>(&Vb[(dt * 32 + qI) * 64 + xsv * 8]);
                    o_acc2[dt] = __builtin_amdgcn_mfma_f32_32x32x16_bf16(va, pB, o_acc2[dt], 0, 0, 0);
                }
            }
        }

        __builtin_amdgcn_sched_barrier(0);
        __builtin_amdgcn_s_barrier();        // reads of bf done before next STAGE overwrites
        __builtin_amdgcn_sched_barrier(0);
        bf ^= 1;
    }
#undef STAGE

    // ---- 2-stage hypercube combine via LDS scratch (128 KB region) ----
    float* scr = (float*)&lsK[0][0][0];
    const int self = (wv << 6) + lane;
    __syncthreads();                          // main loop fully done, LDS reusable

    // Stage A: partner kw^1 (wv^4); keep dt-half = kw&1, exchange the other
    const int dtk = kw & 1;
    f32x16 keepA = o_acc2[dtk];
    f32x16 giveA = o_acc2[dtk ^ 1];
    float* oscA = scr;                        // stride 17: 1024*17*4 = 69632 B
    float* mlA = scr + 1024 * 17;             // 2048 floats
    mlA[self * 2] = m;
    mlA[self * 2 + 1] = l;
#pragma unroll
    for (int i = 0; i < 16; i++) oscA[self * 17 + i] = giveA[i];
    __syncthreads();
    const int peerA = ((wv ^ 4) << 6) + lane;
    float m2 = mlA[peerA * 2], l2 = mlA[peerA * 2 + 1];
    float msh = fmaxf(m, m2);
    float f1 = fexp2(m - msh), f2 = fexp2(m2 - msh);
    float o16[16];
#pragma unroll
    for (int i = 0; i < 16; i++) o16[i] = f1 * keepA[i] + f2 * oscA[peerA * 17 + i];
    float lA_ = f1 * l + f2 * l2;
    float mA_ = msh;
    __syncthreads();                          // stage A reads done before reuse

    // Stage B: partner kw^2 (wv^8); keep quarter qs = kw>>1 (o16[qs*8..+8))
    const int qs = kw >> 1;
    float* oscB = scr;                        // stride 9: 1024*9*4 = 36864 B
    float* mlB = scr + 1024 * 9;
    mlB[self * 2] = mA_;
    mlB[self * 2 + 1] = lA_;
#pragma unroll
    for (int i = 0; i < 8; i++) oscB[self * 9 + i] = o16[(qs ^ 1) * 8 + i];
    __syncthreads();
    const int peerB = ((wv ^ 8) << 6) + lane;
    float mB2 = mlB[peerB * 2], lB2 = mlB[peerB * 2 + 1];
    float msh2 = fmaxf(mA_, mB2);
    float g1 = fexp2(mA_ - msh2), g2 = fexp2(mB2 - msh2);
    const float rl = 1.0f / (g1 * lA_ + g2 * lB2);
    const bool live = (qrow < ql);
    float* obase = out + (size_t)(b * SEQ + qrow) * DM + h * HDIM;
#pragma unroll
    for (int a2 = 0; a2 < 2; a2++) {
        float4 val;
        float v0 = g1 * o16[qs * 8 + a2 * 4 + 0] + g2 * oscB[peerB * 9 + a2 * 4 + 0];
        float v1 = g1 * o16[qs * 8 + a2 * 4 + 1] + g2 * oscB[peerB * 9 + a2 * 4 + 1];
        float v2 = g1 * o16[qs * 8 + a2 * 4 + 2] + g2 * oscB[peerB * 9 + a2 * 4 + 2];
        float v3 = g1 * o16[qs * 8 + a2 * 4 + 3] + g2 * oscB[peerB * 9 + a2 * 4 + 3];
        val.x = live ? v0 * rl : 0.f;
        val.y = live ? v1 * rl : 0.f;
        val.z = live ? v2 * rl : 0.f;
        val.w = live ? v3 * rl : 0.f;
        // d = dtk*32 + (2*qs + a2)*8 + hi*4 + j
        *reinterpret_cast<float4*>(&obase[dtk * 32 + (2 * qs + a2) * 8 + hi * 4]) = val;
    }
}

// ---------------- host launcher ----------------
extern "C" void kernel_launch(void* const* d_in, const int* in_sizes, int n_in,
                              void* d_out, int out_size, void* d_ws, size_t ws_size,
                              hipStream_t stream) {
    const float* Q_seq = (const float*)d_in[0];
    const float* K_seq = (const float*)d_in[1];
    const float* V_seq = (const float*)d_in[2];
    const int* Q_len = (const int*)d_in[3];
    const int* V_len = (const int*)d_in[4];
    const float* WQ = (const float*)d_in[5];
    const float* WK = (const float*)d_in[6];
    const float* WV = (const float*)d_in[7];
    float* out = (float*)d_out;

    const size_t XN = (size_t)MROWS * DM;   // elements per X/out buffer
    const size_t WN = (size_t)DM * DM;
    const size_t need_fast = (6 * XN + 3 * WN) * sizeof(unsigned short);  // ~107 MB

    const int cx_grid = MROWS * DM / 8 / 256;  // 4096
    dim3 cw_grid(DM / 64, DM / 64, 3), cw_blk(64, 4);
    dim3 g_grid(8, 64, 3), g_blk(256);

    if (ws_size >= need_fast) {
        // fused path: 4 launches
        unsigned short* Xq = (unsigned short*)d_ws;
        unsigned short* Xk = Xq + XN;
        unsigned short* Xv = Xk + XN;
        unsigned short* Wq = Xv + XN;
        unsigned short* Wk = Wq + WN;
        unsigned short* Wv = Wk + WN;
        unsigned short* qb = Wv + WN;
        unsigned short* kb = qb + XN;
        unsigned short* vtb = kb + XN;

        convx3_kernel<<<dim3(cx_grid, 3), 256, 0, stream>>>(Q_seq, K_seq, V_seq,
                                                            Xq, Xk, Xv, Q_len, V_len, 0);
        convw3_kernel<<<cw_grid, cw_blk, 0, stream>>>(WQ, WK, WV, Wq, Wk, Wv, 0);
        gemm3_kernel<<<g_grid, g_blk, 0, stream>>>(Xq, Xk, Xv, Wq, Wk, Wv,
                                                   qb, kb, vtb, Q_len, V_len, 0);
        flash_kernel<<<dim3(1024), 1024, 0, stream>>>(qb, kb, vtb, Q_len, V_len, out);
    } else {
        // fallback: shared X/W buffers, sequential per-projection
        unsigned short* Xbuf = (unsigned short*)d_ws;
        unsigned short* Wt = Xbuf + XN;
        unsigned short* qb = Wt + WN;
        unsigned short* kb = qb + XN;
        unsigned short* vtb = kb + XN;
        dim3 cw1(DM / 64, DM / 64, 1);
        dim3 g1(8, 64, 1);
        for (int z = 0; z < 3; z++) {
            convx3_kernel<<<dim3(cx_grid, 1), 256, 0, stream>>>(Q_seq, K_seq, V_seq,
                                                                Xbuf, Xbuf, Xbuf, Q_len, V_len, z);
            convw3_kernel<<<cw1, cw_blk, 0, stream>>>(WQ, WK, WV, Wt, Wt, Wt, z);
            gemm3_kernel<<<g1, g_blk, 0, stream>>>(Xbuf, Xbuf, Xbuf, Wt, Wt, Wt,
                                                   qb, kb, vtb, Q_len, V_len, z);
        }
        flash_kernel<<<dim3(1024), 1024, 0, stream>>>(qb, kb, vtb, Q_len, V_len, out);
    }
}

// Round 24
// 128.256 us; speedup vs baseline: 1.4332x; 1.4332x over previous
//
#include <hip/hip_runtime.h>
#include <hip/hip_bf16.h>
#include <math.h>

// ---- constants for this problem ----
#define BATCH 4
#define SEQ   2048
#define DM    1024
#define NHEAD 16
#define HDIM  64
#define MROWS (BATCH*SEQ)   // 8192

typedef float f32x4 __attribute__((ext_vector_type(4)));
typedef float f32x16 __attribute__((ext_vector_type(16)));
typedef short bf16x8 __attribute__((ext_vector_type(8)));  // 8 bf16 in 4 VGPRs
typedef unsigned int u32x4 __attribute__((ext_vector_type(4)));

typedef __attribute__((address_space(1))) unsigned int as1_u32;
typedef __attribute__((address_space(3))) unsigned int as3_u32;

__device__ __forceinline__ void gld16(const void* g, void* l) {
    // async global->LDS, 16B per lane; LDS dest = wave-uniform base + lane*16
    __builtin_amdgcn_global_load_lds((const as1_u32*)g, (as3_u32*)l, 16, 0, 0);
}

__device__ __forceinline__ unsigned short f2bf(float f) {
    unsigned int u = __float_as_uint(f);
    u += 0x7FFFu + ((u >> 16) & 1u);   // RNE
    return (unsigned short)(u >> 16);
}

__device__ __forceinline__ unsigned int pack2bf(float a, float b) {
    return (unsigned int)f2bf(a) | ((unsigned int)f2bf(b) << 16);
}

__device__ __forceinline__ float fexp2(float x) {
    float r;
    asm("v_exp_f32 %0, %1" : "=v"(r) : "v"(x));
    return r;
}

__device__ __forceinline__ unsigned int cvtpk2(float lo, float hi) {
    unsigned int r;
    asm("v_cvt_pk_bf16_f32 %0, %1, %2" : "=v"(r) : "v"(lo), "v"(hi));
    return r;
}

// lmode: 0 = Q rows (live iff s < ceil32(ql));
//        1 = K rows (skip ALL if vl<=0, else s < ceil64(vl));
//        2 = V rows (ALL if vl<=0, else s < ceil64(vl))
__device__ __forceinline__ int row_limit(int len, int lmode) {
    if (lmode == 0) return (len + 31) & ~31;
    if (lmode == 1) return (len <= 0) ? 0 : ((len + 63) & ~63);
    return (len <= 0) ? SEQ : ((len + 63) & ~63);
}

// ---------------- convert X (fp32 -> bf16), fused Q/K/V, length-skipped ----------------
__global__ __launch_bounds__(256) void convx3_kernel(const float* __restrict__ Q,
                                                     const float* __restrict__ K,
                                                     const float* __restrict__ V,
                                                     unsigned short* __restrict__ Xq,
                                                     unsigned short* __restrict__ Xk,
                                                     unsigned short* __restrict__ Xv,
                                                     const int* __restrict__ Qlen,
                                                     const int* __restrict__ Vlen,
                                                     int zoff) {
    const int z = blockIdx.y + zoff;
    const float* in = (z == 0) ? Q : (z == 1) ? K : V;
    unsigned short* out = (z == 0) ? Xq : (z == 1) ? Xk : Xv;
    int i = blockIdx.x * 256 + threadIdx.x;   // 8-float units; 128 per row
    int row = i >> 7;
    int b = row >> 11, s = row & 2047;
    int lim = (z == 0) ? row_limit(Qlen[b], 0) : row_limit(Vlen[b], z);
    if (s >= lim) return;   // skipped rows never read unmasked
    const float4* p = reinterpret_cast<const float4*>(in) + (size_t)i * 2;
    float4 a = p[0], v = p[1];
    uint4 r;
    r.x = pack2bf(a.x, a.y);
    r.y = pack2bf(a.z, a.w);
    r.z = pack2bf(v.x, v.y);
    r.w = pack2bf(v.z, v.w);
    reinterpret_cast<uint4*>(out)[i] = r;
}

// ---------------- convert + transpose W: [K][N] f32 -> [N][K] bf16, *scale, fused ----------------
__global__ __launch_bounds__(256) void convw3_kernel(const float* __restrict__ WQ,
                                                     const float* __restrict__ WK,
                                                     const float* __restrict__ WV,
                                                     unsigned short* __restrict__ Oq,
                                                     unsigned short* __restrict__ Ok,
                                                     unsigned short* __restrict__ Ov,
                                                     int zoff) {
    const int z = blockIdx.z + zoff;
    const float* in = (z == 0) ? WQ : (z == 1) ? WK : WV;
    unsigned short* out = (z == 0) ? Oq : (z == 1) ? Ok : Ov;
    const float scale = (z == 0) ? 0.125f * 1.44269504088896340736f : 1.0f;
    __shared__ float tile[64][65];
    int n0 = blockIdx.x * 64, k0 = blockIdx.y * 64;
    int tx = threadIdx.x, ty = threadIdx.y;  // (64,4)
#pragma unroll
    for (int i = 0; i < 64; i += 4)
        tile[ty + i][tx] = in[(size_t)(k0 + ty + i) * DM + n0 + tx];
    __syncthreads();
#pragma unroll
    for (int i = 0; i < 64; i += 4)
        out[(size_t)(n0 + ty + i) * DM + k0 + tx] = f2bf(tile[tx][ty + i] * scale);
}

// ---------------- fused GEMM: z selects (A,W,out,mode) ----------------
// z=0: q = Xq@WQt -> [B,H,S,D]; z=1: k = Xk@WKt -> [B,H,S,D]; z=2: v -> [B,H,D,S]
// R19-proven form (empirical floor ~62us): BK=32 counted-vmcnt + T2 swizzle + XCD remap.
__global__ __launch_bounds__(256) void gemm3_kernel(const unsigned short* __restrict__ Xq,
                                                    const unsigned short* __restrict__ Xk,
                                                    const unsigned short* __restrict__ Xv,
                                                    const unsigned short* __restrict__ Wq,
                                                    const unsigned short* __restrict__ Wk,
                                                    const unsigned short* __restrict__ Wv,
                                                    unsigned short* __restrict__ qo,
                                                    unsigned short* __restrict__ ko,
                                                    unsigned short* __restrict__ vo,
                                                    const int* __restrict__ Qlen,
                                                    const int* __restrict__ Vlen,
                                                    int zoff) {
    const int z = blockIdx.z + zoff;
    const unsigned short* A = (z == 0) ? Xq : (z == 1) ? Xk : Xv;
    const unsigned short* Bt = (z == 0) ? Wq : (z == 1) ? Wk : Wv;
    unsigned short* out = (z == 0) ? qo : (z == 1) ? ko : vo;
    const int vmode = (z == 2);
    // bijective tile remap: mt = (by>>3)*8 + bx, nt = by&7  (XCD = bx)
    const int mt_ = (blockIdx.y >> 3) * 8 + blockIdx.x;
    const int nt_ = blockIdx.y & 7;
    const int m0 = mt_ << 7, n0 = nt_ << 7;
    {   // block-uniform length skip: 128-row tile lies within one batch
        int b = m0 >> 11, s0 = m0 & 2047;
        int len = (z == 0) ? Qlen[b] : Vlen[b];
        if (s0 >= row_limit(len, z)) return;
    }
    __shared__ unsigned short lA[2][128 * 32];
    __shared__ unsigned short lB[2][128 * 32];
    const int tid = threadIdx.x, lane = tid & 63, wave = tid >> 6;
    const int wr = wave >> 1, wc = wave & 1;
    const int col = lane & 15, grp = lane >> 4;

    f32x4 acc[4][4] = {};

    const int srow = tid >> 2;
    const int sx = (tid & 3) ^ (srow & 3);   // pre-swizzled source segment (rule #21)
    const unsigned short* srcA0 = A + (size_t)(m0 + srow) * DM + sx * 8;
    const unsigned short* srcA1 = srcA0 + (size_t)64 * DM;   // (row+64)&3 == row&3
    const unsigned short* srcB0 = Bt + (size_t)(n0 + srow) * DM + sx * 8;
    const unsigned short* srcB1 = srcB0 + (size_t)64 * DM;

#define STAGEG(BF, K0) do {                                   \
        gld16(srcA0 + (K0), &lA[BF][wave * 512]);             \
        gld16(srcA1 + (K0), &lA[BF][2048 + wave * 512]);      \
        gld16(srcB0 + (K0), &lB[BF][wave * 512]);             \
        gld16(srcB1 + (K0), &lB[BF][2048 + wave * 512]);      \
    } while (0)

    STAGEG(0, 0);                          // prologue prefetch (stays in flight)

    const int xs = (grp ^ (col & 3)) * 8;  // swizzled read segment (row&3 == col&3)
    int bf = 0;
    for (int k0 = 0; k0 < DM; k0 += 32) {
        if (k0 + 32 < DM) {
            STAGEG(bf ^ 1, k0 + 32);       // issue next tile (8 outstanding now)
            asm volatile("s_waitcnt vmcnt(4)" ::: "memory");   // cur tile's 4 landed
        } else {
            asm volatile("s_waitcnt vmcnt(0)" ::: "memory");
        }
        __builtin_amdgcn_sched_barrier(0);
        __builtin_amdgcn_s_barrier();      // every wave confirmed its cur-tile quarter
        __builtin_amdgcn_sched_barrier(0);

        bf16x8 af[4], bfr[4];
#pragma unroll
        for (int mt = 0; mt < 4; mt++)
            af[mt] = *reinterpret_cast<const bf16x8*>(&lA[bf][(wr * 64 + mt * 16 + col) * 32 + xs]);
#pragma unroll
        for (int nt = 0; nt < 4; nt++)
            bfr[nt] = *reinterpret_cast<const bf16x8*>(&lB[bf][(wc * 64 + nt * 16 + col) * 32 + xs]);
#pragma unroll
        for (int mt = 0; mt < 4; mt++)
#pragma unroll
            for (int nt = 0; nt < 4; nt++)
                acc[mt][nt] = __builtin_amdgcn_mfma_f32_16x16x32_bf16(af[mt], bfr[nt], acc[mt][nt], 0, 0, 0);

        __builtin_amdgcn_sched_barrier(0);
        __builtin_amdgcn_s_barrier();      // all reads of bf done (MFMA forced lgkm drain)
        __builtin_amdgcn_sched_barrier(0);
        bf ^= 1;
    }
#undef STAGEG

#pragma unroll
    for (int mt = 0; mt < 4; mt++) {
        int rowb = m0 + wr * 64 + mt * 16 + grp * 4;
#pragma unroll
        for (int nt = 0; nt < 4; nt++) {
            int c = n0 + wc * 64 + nt * 16 + col;
            int h = c >> 6, d = c & 63;
            if (vmode == 0) {
#pragma unroll
                for (int r = 0; r < 4; r++) {
                    int rr = rowb + r;
                    int b = rr >> 11, s = rr & 2047;
                    out[((((size_t)(b * NHEAD + h)) << 11) + s) * HDIM + d] = f2bf(acc[mt][nt][r]);
                }
            } else {
                // transposed: 4 consecutive s -> one 8B store at [(b,h,d)][s]
                int b = rowb >> 11, s = rowb & 2047;
                uint2 pk;
                pk.x = pack2bf(acc[mt][nt][0], acc[mt][nt][1]);
                pk.y = pack2bf(acc[mt][nt][2], acc[mt][nt][3]);
                *reinterpret_cast<uint2*>(
                    &out[(((size_t)(b * NHEAD + h)) * HDIM + d) * SEQ + s]) = pk;
            }
        }
    }
}

// ---------------- flash attention: 128 q-rows/block, 8 waves = 4 q-subtiles x 2 KV-streams ----------------
// grid 1024; block 512. Wave (qw,kw): qw owns q-rows [q0+32qw, +32); kw=0 walks
// even KV tiles, kw=1 odd (private dbuf LDS per stream). Counted-vmcnt + raw
// barriers per round (R16-proven discipline): loads stay in flight across rounds.
// T13 defer-rescale (THR=8, log2 domain). End: kw-pair combine via LDS scratch.
__global__ __launch_bounds__(512) void flash_kernel(const unsigned short* __restrict__ qm,
                                                    const unsigned short* __restrict__ km,
                                                    const unsigned short* __restrict__ vtm,
                                                    const int* __restrict__ Qlen,
                                                    const int* __restrict__ Vlen,
                                                    float* __restrict__ out) {
    // XCD swizzle: XCD = raw%8 = h%8 -> each XCD streams only 2 heads' K/V
    const int raw = blockIdx.x;
    const int x = raw & 7, y = raw >> 3;
    const int qt = y & 15, z = y >> 4;
    const int h = x + ((z & 1) << 3);
    const int b = z >> 1;
    const int q0 = qt << 7;                  // 128 q-rows per block
    const int lane = threadIdx.x & 63, wv = threadIdx.x >> 6;
    const int qw = wv & 3, kw = wv >> 2;
    const int qI = lane & 31, hi = lane >> 5;
    const int ql = Qlen[b], vl = Vlen[b];
    const int qrow = q0 + qw * 32 + qI;      // this wave's q-row for this lane

    if (q0 >= ql) {  // block-uniform: whole 128-row tile query-masked -> zeros
        int r = threadIdx.x >> 2;            // 0..127
        int c0 = (threadIdx.x & 3) * 16;
        float* p = out + (size_t)(b * SEQ + q0 + r) * DM + h * HDIM + c0;
        float4 z4 = {0.f, 0.f, 0.f, 0.f};
        reinterpret_cast<float4*>(p)[0] = z4;
        reinterpret_cast<float4*>(p)[1] = z4;
        reinterpret_cast<float4*>(p)[2] = z4;
        reinterpret_cast<float4*>(p)[3] = z4;
        return;
    }

    const bool uniform = (vl <= 0);      // fp32 ref collapse: uniform weights over ALL keys
    const int eff = uniform ? SEQ : vl;
    const int nkv = (eff + 63) >> 6;

    const size_t hb = ((size_t)(b * NHEAD + h)) << 11;  // *SEQ
    const unsigned short* qbase = qm + hb * HDIM;
    const unsigned short* kbase = km + hb * HDIM;
    const unsigned short* vbase = vtm + hb * HDIM;      // [64][SEQ] per (b,h)

    // per-stream double-buffered K tile [64 keys][64 d] and V^T tile [64 d][64 keys];
    // LDS[row][slot] holds global[row][slot ^ (row&7)]. 64 KB total.
    __shared__ __align__(16) unsigned short lsK[2][2][64 * 64];
    __shared__ __align__(16) unsigned short lsV[2][2][64 * 64];

    const int r8 = lane >> 3, cs = lane & 7;
    const int sx = cs ^ r8;                               // (slot ^ (row&7))
    const size_t offK0 = (size_t)(qw * 16 + r8) * HDIM + sx * 8;
    const size_t offK1 = offK0 + (size_t)8 * HDIM;
    const size_t offV0 = (size_t)(qw * 16 + r8) * SEQ + sx * 8;
    const size_t offV1 = offV0 + (size_t)8 * SEQ;

#define STAGE(BF, T) do {                                                \
        const int kv0_ = (T) << 6;                                       \
        const unsigned short* gk_ = kbase + (size_t)kv0_ * HDIM;         \
        const unsigned short* gv_ = vbase + kv0_;                        \
        gld16(gk_ + offK0, &lsK[kw][BF][(qw * 16) * 64]);                \
        gld16(gk_ + offK1, &lsK[kw][BF][(qw * 16 + 8) * 64]);            \
        gld16(gv_ + offV0, &lsV[kw][BF][(qw * 16) * 64]);                \
        gld16(gv_ + offV1, &lsV[kw][BF][(qw * 16 + 8) * 64]);            \
    } while (0)

    // Q B-fragment (held all tiles): col j = q = qI, k-chunk = sp*16 + hi*8
    bf16x8 qB[4];
#pragma unroll
    for (int sp = 0; sp < 4; sp++)
        qB[sp] = *reinterpret_cast<const bf16x8*>(&qbase[(size_t)qrow * HDIM + sp * 16 + hi * 8]);

    f32x16 o_acc2[2] = {};
    float m = -3.0e38f, l = 0.f;
    const int q7 = qI & 7;                   // row&7 for all K/V rows this lane reads

    const int rounds = (nkv + 1) >> 1;
    if (kw < nkv) STAGE(0, kw);              // round-0 tile for own stream (in flight)

    int bf = 0;
    for (int r = 0; r < rounds; r++) {
        const int tcur = 2 * r + kw;
        const int tnext = tcur + 2;
        if (tnext < nkv) {
            STAGE(bf ^ 1, tnext);            // issue next tile (8 outstanding)
            asm volatile("s_waitcnt vmcnt(4)" ::: "memory");   // cur tile's 4 landed
        } else {
            asm volatile("s_waitcnt vmcnt(0)" ::: "memory");
        }
        __builtin_amdgcn_sched_barrier(0);
        __builtin_amdgcn_s_barrier();        // all waves' parts of cur tile visible
        __builtin_amdgcn_sched_barrier(0);

        if (tcur < nkv) {
            const int kv0 = tcur << 6;

            // ---- S^T = K Q^T from LDS: two 32-key tiles ----
            f32x16 st2[2] = {};
            const unsigned short* Kb = &lsK[kw][bf][0];
#pragma unroll
            for (int kt = 0; kt < 2; kt++)
#pragma unroll
                for (int sp = 0; sp < 4; sp++) {
                    int xsk = (sp * 2 + hi) ^ q7;
                    bf16x8 ka = *reinterpret_cast<const bf16x8*>(&Kb[(kt * 32 + qI) * 64 + xsk * 8]);
                    st2[kt] = __builtin_amdgcn_mfma_f32_32x32x16_bf16(ka, qB[sp], st2[kt], 0, 0, 0);
                }

            // ---- mask: key(t,r) = kv0 + t*32 + (r&3) + 8*(r>>2) + 4*hi ----
            if (uniform) {
#pragma unroll
                for (int t = 0; t < 2; t++)
#pragma unroll
                    for (int rr = 0; rr < 16; rr++) st2[t][rr] = 0.f;
            } else if (kv0 + 64 > eff) {
#pragma unroll
                for (int t = 0; t < 2; t++)
#pragma unroll
                    for (int rr = 0; rr < 16; rr++)
                        if (kv0 + t * 32 + (rr & 3) + 8 * (rr >> 2) + 4 * hi >= eff)
                            st2[t][rr] = -1e30f;
            }

            // ---- online softmax: tree-max + T13 defer-rescale (THR=8, log2 domain) ----
            float tm8[8];
#pragma unroll
            for (int rr = 0; rr < 8; rr++)
                tm8[rr] = fmaxf(fmaxf(st2[0][rr], st2[0][rr + 8]), fmaxf(st2[1][rr], st2[1][rr + 8]));
            float tm4[4];
#pragma unroll
            for (int rr = 0; rr < 4; rr++) tm4[rr] = fmaxf(tm8[rr], tm8[rr + 4]);
            float mx = fmaxf(fmaxf(tm4[0], tm4[1]), fmaxf(tm4[2], tm4[3]));
            mx = fmaxf(mx, __shfl_xor(mx, 32));
            if (!__all(mx - m <= 8.0f)) {    // rescale only when max moved (wave-uniform)
                float mnew = fmaxf(m, mx);
                float sc = fexp2(m - mnew);
                l *= sc;
                o_acc2[0] *= sc;
                o_acc2[1] *= sc;
                m = mnew;
            }
#pragma unroll
            for (int t = 0; t < 2; t++)
#pragma unroll
                for (int rr = 0; rr < 16; rr++) st2[t][rr] = fexp2(st2[t][rr] - m);
            float ts8[8];
#pragma unroll
            for (int rr = 0; rr < 8; rr++)
                ts8[rr] = (st2[0][rr] + st2[0][rr + 8]) + (st2[1][rr] + st2[1][rr + 8]);
            float ts4[4];
#pragma unroll
            for (int rr = 0; rr < 4; rr++) ts4[rr] = ts8[rr] + ts8[rr + 4];
            float rs = (ts4[0] + ts4[1]) + (ts4[2] + ts4[3]);
            rs += __shfl_xor(rs, 32);
            l += rs;

            // ---- pack P pairs ----
            unsigned int pk[2][8];
#pragma unroll
            for (int t = 0; t < 2; t++)
#pragma unroll
                for (int p = 0; p < 8; p++)
                    pk[t][p] = cvtpk2(st2[t][2 * p], st2[t][2 * p + 1]);

            // ---- redistribute to PV B-frag (shfl_xor, proven) + PV MFMA ----
            const unsigned short* Vb = &lsV[kw][bf][0];
#pragma unroll
            for (int ks = 0; ks < 4; ks++) {
                const int t = ks >> 1, c = (ks & 1) * 4;
                unsigned int sel0 = pk[t][c], sel1 = pk[t][c + 1];
                unsigned int sel2 = pk[t][c + 2], sel3 = pk[t][c + 3];
                unsigned int sendA = hi ? sel0 : sel2;
                unsigned int sendB = hi ? sel1 : sel3;
                unsigned int gotA = __shfl_xor(sendA, 32);
                unsigned int gotB = __shfl_xor(sendB, 32);
                u32x4 u;
                u[0] = hi ? gotA : sel0;
                u[1] = hi ? gotB : sel1;
                u[2] = hi ? sel2 : gotA;
                u[3] = hi ? sel3 : gotB;
                bf16x8 pB = __builtin_bit_cast(bf16x8, u);
                int xsv = (ks * 2 + hi) ^ q7;
#pragma unroll
                for (int dt = 0; dt < 2; dt++) {
                    bf16x8 va = *reinterpret_cast<const bf16x8*>(&Vb[(dt * 32 + qI) * 64 + xsv * 8]);
                    o_acc2[dt] = __builtin_amdgcn_mfma_f32_32x32x16_bf16(va, pB, o_acc2[dt], 0, 0, 0);
                }
            }
        }

        __builtin_amdgcn_sched_barrier(0);
        __builtin_amdgcn_s_barrier();        // reads of bf done before next STAGE overwrites
        __builtin_amdgcn_sched_barrier(0);
        bf ^= 1;
    }
#undef STAGE

    // ---- kw-pair combine via LDS scratch (stride 17 = conflict-free) ----
    float* base = (float*)&lsK[0][0][0];
    float* osc = base;                       // 512*17 floats = 34816 B
    float* mls = base + 512 * 17;            // 1024 floats (fits in 64KB total)
    const int self = (wv << 6) + lane;
    const int peer = ((wv ^ 4) << 6) + lane;
    // each wave publishes m,l and the o-half it will NOT write (dt = kw^1)
    f32x16 o_keep = (kw == 0) ? o_acc2[0] : o_acc2[1];
    f32x16 o_give = (kw == 0) ? o_acc2[1] : o_acc2[0];
    mls[self * 2] = m;
    mls[self * 2 + 1] = l;
#pragma unroll
    for (int i = 0; i < 16; i++) osc[self * 17 + i] = o_give[i];
    __syncthreads();
    const float m2 = mls[peer * 2], l2 = mls[peer * 2 + 1];
    const float msh = fmaxf(m, m2);
    const float f1 = fexp2(m - msh), f2 = fexp2(m2 - msh);
    const float rl = 1.0f / (f1 * l + f2 * l2);
    const bool live = (qrow < ql);
    float* obase = out + (size_t)(b * SEQ + qrow) * DM + h * HDIM;
#pragma unroll
    for (int a = 0; a < 4; a++) {
        float4 val;
        float v0 = f1 * o_keep[4 * a + 0] + f2 * osc[peer * 17 + 4 * a + 0];
        float v1 = f1 * o_keep[4 * a + 1] + f2 * osc[peer * 17 + 4 * a + 1];
        float v2 = f1 * o_keep[4 * a + 2] + f2 * osc[peer * 17 + 4 * a + 2];
        float v3 = f1 * o_keep[4 * a + 3] + f2 * osc[peer * 17 + 4 * a + 3];
        val.x = live ? v0 * rl : 0.f;
        val.y = live ? v1 * rl : 0.f;
        val.z = live ? v2 * rl : 0.f;
        val.w = live ? v3 * rl : 0.f;
        *reinterpret_cast<float4*>(&obase[kw * 32 + a * 8 + hi * 4]) = val;
    }
}

// ---------------- host launcher ----------------
extern "C" void kernel_launch(void* const* d_in, const int* in_sizes, int n_in,
                              void* d_out, int out_size, void* d_ws, size_t ws_size,
                              hipStream_t stream) {
    const float* Q_seq = (const float*)d_in[0];
    const float* K_seq = (const float*)d_in[1];
    const float* V_seq = (const float*)d_in[2];
    const int* Q_len = (const int*)d_in[3];
    const int* V_len = (const int*)d_in[4];
    const float* WQ = (const float*)d_in[5];
    const float* WK = (const float*)d_in[6];
    const float* WV = (const float*)d_in[7];
    float* out = (float*)d_out;

    const size_t XN = (size_t)MROWS * DM;   // elements per X/out buffer
    const size_t WN = (size_t)DM * DM;
    const size_t need_fast = (6 * XN + 3 * WN) * sizeof(unsigned short);  // ~107 MB

    const int cx_grid = MROWS * DM / 8 / 256;  // 4096
    dim3 cw_grid(DM / 64, DM / 64, 3), cw_blk(64, 4);
    dim3 g_grid(8, 64, 3), g_blk(256);

    if (ws_size >= need_fast) {
        // fused path: 4 launches
        unsigned short* Xq = (unsigned short*)d_ws;
        unsigned short* Xk = Xq + XN;
        unsigned short* Xv = Xk + XN;
        unsigned short* Wq = Xv + XN;
        unsigned short* Wk = Wq + WN;
        unsigned short* Wv = Wk + WN;
        unsigned short* qb = Wv + WN;
        unsigned short* kb = qb + XN;
        unsigned short* vtb = kb + XN;

        convx3_kernel<<<dim3(cx_grid, 3), 256, 0, stream>>>(Q_seq, K_seq, V_seq,
                                                            Xq, Xk, Xv, Q_len, V_len, 0);
        convw3_kernel<<<cw_grid, cw_blk, 0, stream>>>(WQ, WK, WV, Wq, Wk, Wv, 0);
        gemm3_kernel<<<g_grid, g_blk, 0, stream>>>(Xq, Xk, Xv, Wq, Wk, Wv,
                                                   qb, kb, vtb, Q_len, V_len, 0);
        flash_kernel<<<dim3(1024), 512, 0, stream>>>(qb, kb, vtb, Q_len, V_len, out);
    } else {
        // fallback: shared X/W buffers, sequential per-projection
        unsigned short* Xbuf = (unsigned short*)d_ws;
        unsigned short* Wt = Xbuf + XN;
        unsigned short* qb = Wt + WN;
        unsigned short* kb = qb + XN;
        unsigned short* vtb = kb + XN;
        dim3 cw1(DM / 64, DM / 64, 1);
        dim3 g1(8, 64, 1);
        for (int z = 0; z < 3; z++) {
            convx3_kernel<<<dim3(cx_grid, 1), 256, 0, stream>>>(Q_seq, K_seq, V_seq,
                                                                Xbuf, Xbuf, Xbuf, Q_len, V_len, z);
            convw3_kernel<<<cw1, cw_blk, 0, stream>>>(WQ, WK, WV, Wt, Wt, Wt, z);
            gemm3_kernel<<<g1, g_blk, 0, stream>>>(Xbuf, Xbuf, Xbuf, Wt, Wt, Wt,
                                                   qb, kb, vtb, Q_len, V_len, z);
        }
        flash_kernel<<<dim3(1024), 512, 0, stream>>>(qb, kb, vtb, Q_len, V_len, out);
    }
}